// Round 1
// baseline (32333.078 us; speedup 1.0000x reference)
//
#include <hip/hip_runtime.h>

// ============================================================================
// 2-layer LSTM (B=256, T=1024, H=512, in=1) + linear head. fp32 in/out.
//
// R1 design: single persistent kernel, 192 WGs x 512 thr (1-2 blocks/CU, all
// co-resident since 192 <= 256 CUs at 64KB LDS each). Layer-pipelined:
//   blocks 0..63   : layer0, computes p_s   (reads p_{s-1})
//   blocks 64..191 : layer1, computes q_{s-1} (reads p_{s-1}, q_{s-2})
// One hand-rolled grid barrier per macro-step (1025 total).
// Weights LDS-resident fp16 (pre-tiled into MFMA B-fragment order).
// h carried as fp16 hi + (lo*1024) split; MFMA f32_16x16x32_f16, fp32 accum,
// fp32 cell state in registers. Accuracy est ~1e-4 vs threshold 3.27e-4.
// h exchange: relaxed agent-scope stores (to LLC) + per-step agent-acquire
// fence (L1/L2 invalidate) + plain vectorized loads (L2-cached per XCD).
// ============================================================================

typedef _Float16 f16;
typedef _Float16 f16x8 __attribute__((ext_vector_type(8)));
typedef float f32x4 __attribute__((ext_vector_type(4)));

#define NB 256
#define NT_ 1024
#define NH 512
#define NGRID 192

__device__ __forceinline__ float sigm(float x)  { return 1.0f / (1.0f + __expf(-x)); }
__device__ __forceinline__ float tanhx(float x) { return 2.0f / (1.0f + __expf(-2.0f * x)) - 1.0f; }

// ---------------------------------------------------------------------------
// Prologue: transpose input [B,T] -> xT [T,B]
__global__ void prep_xT(const float* __restrict__ inp, float* __restrict__ xT) {
  int g = blockIdx.x * 256 + threadIdx.x;       // 262144 threads
  int t = g >> 8, b = g & 255;
  xT[t * NB + b] = inp[b * NT_ + t];
}

// ---------------------------------------------------------------------------
// Prologue: convert fp32 weights -> fp16, pre-tiled into MFMA B-fragment order.
// mat 0: Wh0, 32 slices (16 hid units -> 64 gcols, 4 ntiles [i16|f16|g16|o16])
// mat 1: Wx1, mat 2: Wh1: 64 slices (8 hid units -> 32 gcols, 2 ntiles
//        [i8 f8 | g8 o8], gate = nt*2 + (cl>>3))
// Fragment element: B[k = kt*32 + (lane>>4)*8 + j][col], lane's 8 elems
// stored contiguously (16B) for ds_read_b128.
__global__ void prep_w(const float* __restrict__ Wh0,
                       const float* __restrict__ Wx1,
                       const float* __restrict__ Wh1,
                       f16* __restrict__ dst) {
  int g = blockIdx.x * 256 + threadIdx.x;       // 3 * 2^20 threads
  int mat = g >> 20;
  int r = g & 0xFFFFF;
  int j  = r & 7;
  int ln = (r >> 3) & 63;
  int cl = ln & 15, qd = ln >> 4;
  int k, gcol; size_t di; const float* W;
  if (mat == 0) {
    int nt = (r >> 9) & 3;
    int kt = (r >> 11) & 15;
    int hb = (r >> 15) & 31;
    W = Wh0;
    gcol = nt * 512 + hb * 16 + cl;
    k = kt * 32 + qd * 8 + j;
    di = (size_t)hb * 32768 + ((size_t)(kt * 4 + nt) * 64 + ln) * 8 + j;
  } else {
    int nt = (r >> 9) & 1;
    int kt = (r >> 10) & 15;
    int hb = (r >> 14) & 63;
    W = (mat == 1) ? Wx1 : Wh1;
    int gate = nt * 2 + (cl >> 3);
    gcol = gate * 512 + hb * 8 + (cl & 7);
    k = kt * 32 + qd * 8 + j;
    di = (size_t)mat * 1048576 + (size_t)hb * 16384 +
         ((size_t)(kt * 2 + nt) * 64 + ln) * 8 + j;
  }
  dst[di] = (f16)W[(size_t)k * 2048 + gcol];
}

// ---------------------------------------------------------------------------
__global__ __launch_bounds__(512) void lstm_main(
    const float* __restrict__ xT,       // [T][B]
    const f16*  __restrict__ wsl,       // tiled weight slices (6 MB)
    const float* __restrict__ wx0,      // [2048]
    const float* __restrict__ bias0,    // [2048]
    const float* __restrict__ bias1,    // [2048]
    const float* __restrict__ wf,       // [512]
    const float* __restrict__ bfp,      // [1]
    unsigned short* p_hi, unsigned short* p_lo,   // [2][B][H] fp16 bits
    unsigned short* q_hi, unsigned short* q_lo,   // [2][B][H]
    unsigned int* ctr,
    float* out)                          // [B][T]
{
  extern __shared__ char smem[];
  const int tid = threadIdx.x;
  const int wv  = tid >> 6;
  const int ln  = tid & 63;
  const int qd  = ln >> 4;
  const int cl  = ln & 15;
  const int bx  = blockIdx.x;
  const bool isL0 = (bx < 64);
  const float LO_SCALE = 1.0f / 1024.0f;

  // ---- stage this WG's weight slice(s) into LDS (once) ----
  int hb, rb;
  if (isL0) {
    hb = bx >> 1;
    rb = (bx & 1) * 128 + wv * 16;   // this wave's 16-row batch tile base
    const int4* s0 = (const int4*)((const char*)wsl + (size_t)hb * 65536);
    int4* d = (int4*)smem;
    for (int i = tid; i < 4096; i += 512) d[i] = s0[i];
  } else {
    int ix = bx - 64;
    hb = ix >> 1;
    rb = (ix & 1) * 128 + wv * 16;
    const int4* s1 = (const int4*)((const char*)wsl + (1u << 21) + (size_t)hb * 32768);
    const int4* s2 = (const int4*)((const char*)wsl + (2u << 21) + (size_t)hb * 32768);
    int4* d = (int4*)smem;
    for (int i = tid; i < 2048; i += 512) { d[i] = s1[i]; d[2048 + i] = s2[i]; }
  }
  __syncthreads();

  // ---- loop-invariant per-lane constants ----
  float wx0v[4], b0c[4];
  float b1c0 = 0.f, b1c1 = 0.f, wfv = 0.f, bfv = 0.f;
  if (isL0) {
#pragma unroll
    for (int nt = 0; nt < 4; ++nt) {
      int gc = nt * 512 + hb * 16 + cl;
      wx0v[nt] = wx0[gc];
      b0c[nt]  = bias0[gc];
    }
  } else {
    int u = cl & 7, g01 = cl >> 3;
    b1c0 = bias1[g01 * 512 + hb * 8 + u];
    b1c1 = bias1[(2 + g01) * 512 + hb * 8 + u];
    wfv  = wf[hb * 8 + u];
    bfv  = (hb == 0) ? bfp[0] : 0.0f;
  }
  float cst[4] = {0.f, 0.f, 0.f, 0.f};   // cell state, lives in VGPRs

  for (int s = 0; s <= NT_; ++s) {
    if (isL0) {
      if (s < NT_) {
        // read p_{s-1} (parity (s-1)&1 == (s+1)&1), write p_s (parity s&1)
        const unsigned short* shi = p_hi + (size_t)((s + 1) & 1) * (NB * NH);
        const unsigned short* slo = p_lo + (size_t)((s + 1) & 1) * (NB * NH);
        const f16* ah = (const f16*)(shi + (size_t)(rb + cl) * NH) + qd * 8;
        const f16* al = (const f16*)(slo + (size_t)(rb + cl) * NH) + qd * 8;
        const f16x8* wlds = (const f16x8*)smem;
        f32x4 acc[4]  = {{0,0,0,0},{0,0,0,0},{0,0,0,0},{0,0,0,0}};
        f32x4 accL[4] = {{0,0,0,0},{0,0,0,0},{0,0,0,0},{0,0,0,0}};
#pragma unroll
        for (int kt = 0; kt < 16; ++kt) {
          f16x8 a0 = *(const f16x8*)(ah + kt * 32);
          f16x8 a1 = *(const f16x8*)(al + kt * 32);
#pragma unroll
          for (int nt = 0; nt < 4; ++nt) {
            f16x8 bw = wlds[(kt * 4 + nt) * 64 + ln];
            acc[nt]  = __builtin_amdgcn_mfma_f32_16x16x32_f16(a0, bw, acc[nt], 0, 0, 0);
            accL[nt] = __builtin_amdgcn_mfma_f32_16x16x32_f16(a1, bw, accL[nt], 0, 0, 0);
          }
        }
        const int wpar = s & 1;
#pragma unroll
        for (int e = 0; e < 4; ++e) {
          int b = rb + qd * 4 + e;
          float xv = xT[s * NB + b];
          float gi = acc[0][e] + accL[0][e] * LO_SCALE + xv * wx0v[0] + b0c[0];
          float gf = acc[1][e] + accL[1][e] * LO_SCALE + xv * wx0v[1] + b0c[1];
          float gg = acc[2][e] + accL[2][e] * LO_SCALE + xv * wx0v[2] + b0c[2];
          float go = acc[3][e] + accL[3][e] * LO_SCALE + xv * wx0v[3] + b0c[3];
          float ii = sigm(gi), ff = sigm(gf), tg = tanhx(gg), oo = sigm(go);
          cst[e] = ff * cst[e] + ii * tg;
          float h = oo * tanhx(cst[e]);
          f16 hh = (f16)h;
          f16 hl = (f16)((h - (float)hh) * 1024.0f);
          size_t off = (size_t)wpar * (NB * NH) + (size_t)b * NH + hb * 16 + cl;
          __hip_atomic_store(p_hi + off, __builtin_bit_cast(unsigned short, hh),
                             __ATOMIC_RELAXED, __HIP_MEMORY_SCOPE_AGENT);
          __hip_atomic_store(p_lo + off, __builtin_bit_cast(unsigned short, hl),
                             __ATOMIC_RELAXED, __HIP_MEMORY_SCOPE_AGENT);
        }
      }
    } else {
      if (s >= 1) {
        // compute q_{s-1}: reads p_{s-1} (parity (s+1)&1), q_{s-2} (parity s&1),
        // writes q_{s-1} (parity (s-1)&1)
        const unsigned short* phi_ = p_hi + (size_t)((s + 1) & 1) * (NB * NH);
        const unsigned short* plo_ = p_lo + (size_t)((s + 1) & 1) * (NB * NH);
        const unsigned short* qhi_ = q_hi + (size_t)(s & 1) * (NB * NH);
        const unsigned short* qlo_ = q_lo + (size_t)(s & 1) * (NB * NH);
        const f16* aph = (const f16*)(phi_ + (size_t)(rb + cl) * NH) + qd * 8;
        const f16* apl = (const f16*)(plo_ + (size_t)(rb + cl) * NH) + qd * 8;
        const f16* aqh = (const f16*)(qhi_ + (size_t)(rb + cl) * NH) + qd * 8;
        const f16* aql = (const f16*)(qlo_ + (size_t)(rb + cl) * NH) + qd * 8;
        const f16x8* wx_ = (const f16x8*)smem;
        const f16x8* wh_ = (const f16x8*)(smem + 32768);
        f32x4 acc[2]  = {{0,0,0,0},{0,0,0,0}};
        f32x4 accL[2] = {{0,0,0,0},{0,0,0,0}};
#pragma unroll
        for (int kt = 0; kt < 16; ++kt) {
          f16x8 ph = *(const f16x8*)(aph + kt * 32);
          f16x8 pl = *(const f16x8*)(apl + kt * 32);
          f16x8 qh = *(const f16x8*)(aqh + kt * 32);
          f16x8 ql = *(const f16x8*)(aql + kt * 32);
#pragma unroll
          for (int nt = 0; nt < 2; ++nt) {
            f16x8 bxf = wx_[(kt * 2 + nt) * 64 + ln];
            f16x8 bhf = wh_[(kt * 2 + nt) * 64 + ln];
            acc[nt]  = __builtin_amdgcn_mfma_f32_16x16x32_f16(ph, bxf, acc[nt], 0, 0, 0);
            accL[nt] = __builtin_amdgcn_mfma_f32_16x16x32_f16(pl, bxf, accL[nt], 0, 0, 0);
            acc[nt]  = __builtin_amdgcn_mfma_f32_16x16x32_f16(qh, bhf, acc[nt], 0, 0, 0);
            accL[nt] = __builtin_amdgcn_mfma_f32_16x16x32_f16(ql, bhf, accL[nt], 0, 0, 0);
          }
        }
        const int wpar = (s - 1) & 1;
        const int tOut = s - 1;
        const bool hiHalf = (cl < 8);
        const int u = cl & 7;
#pragma unroll
        for (int e = 0; e < 4; ++e) {
          int b = rb + qd * 4 + e;
          float v0 = acc[0][e] + accL[0][e] * LO_SCALE + b1c0;  // i (cl<8) / f
          float v1 = acc[1][e] + accL[1][e] * LO_SCALE + b1c1;  // g (cl<8) / o
          float w0 = __shfl_xor(v0, 8, 16);
          float w1 = __shfl_xor(v1, 8, 16);
          float gi = hiHalf ? v0 : w0;
          float gf = hiHalf ? w0 : v0;
          float gg = hiHalf ? v1 : w1;
          float go = hiHalf ? w1 : v1;
          float ii = sigm(gi), ff = sigm(gf), tg = tanhx(gg), oo = sigm(go);
          cst[e] = ff * cst[e] + ii * tg;
          float h = oo * tanhx(cst[e]);
          size_t off = (size_t)wpar * (NB * NH) + (size_t)b * NH + hb * 8 + u;
          f16 hh = (f16)h;
          if (hiHalf) {
            __hip_atomic_store(q_hi + off, __builtin_bit_cast(unsigned short, hh),
                               __ATOMIC_RELAXED, __HIP_MEMORY_SCOPE_AGENT);
          } else {
            f16 hl = (f16)((h - (float)hh) * 1024.0f);
            __hip_atomic_store(q_lo + off, __builtin_bit_cast(unsigned short, hl),
                               __ATOMIC_RELAXED, __HIP_MEMORY_SCOPE_AGENT);
          }
          float po = hiHalf ? (wfv * h) : 0.0f;
#pragma unroll
          for (int m = 1; m < 16; m <<= 1) po += __shfl_xor(po, m, 16);
          if (cl == 0) atomicAdd(out + (size_t)b * NT_ + tOut, po + bfv);
        }
      }
    }

    // ---- grid barrier (all 192 WGs, every step) ----
    __syncthreads();   // drains vmcnt: all agent stores reached LLC
    if (tid == 0) {
      __hip_atomic_fetch_add(ctr, 1u, __ATOMIC_RELAXED, __HIP_MEMORY_SCOPE_AGENT);
      const unsigned tgt = (unsigned)NGRID * (unsigned)(s + 1);
      while (__hip_atomic_load(ctr, __ATOMIC_RELAXED, __HIP_MEMORY_SCOPE_AGENT) < tgt)
        __builtin_amdgcn_s_sleep(2);
    }
    __syncthreads();
    // invalidate L1/L2 so next step's plain h-loads can't see stale lines
    __builtin_amdgcn_fence(__ATOMIC_ACQUIRE, "agent");
  }
}

// ---------------------------------------------------------------------------
extern "C" void kernel_launch(void* const* d_in, const int* in_sizes, int n_in,
                              void* d_out, int out_size, void* d_ws, size_t ws_size,
                              hipStream_t stream) {
  (void)in_sizes; (void)n_in; (void)out_size; (void)ws_size;
  const float* inp = (const float*)d_in[0];
  const float* Wx0 = (const float*)d_in[1];
  const float* Wh0 = (const float*)d_in[2];
  const float* b0  = (const float*)d_in[3];
  const float* Wx1 = (const float*)d_in[4];
  const float* Wh1 = (const float*)d_in[5];
  const float* b1  = (const float*)d_in[6];
  const float* Wf  = (const float*)d_in[7];
  const float* bf  = (const float*)d_in[8];

  const size_t kBH    = (size_t)NB * NH;          // 131072 elems
  const size_t OFF_W  = 0;                        // 6 MiB of tiled fp16 weights
  const size_t OFF_XT = 6u << 20;                 // 1 MiB xT
  const size_t OFF_PHI = OFF_XT + (size_t)NT_ * NB * 4;
  const size_t OFF_PLO = OFF_PHI + 2 * kBH * 2;
  const size_t OFF_QHI = OFF_PLO + 2 * kBH * 2;
  const size_t OFF_QLO = OFF_QHI + 2 * kBH * 2;
  const size_t OFF_CTR = OFF_QLO + 2 * kBH * 2;

  char* ws = (char*)d_ws;
  f16* wsl = (f16*)(ws + OFF_W);
  float* xT = (float*)(ws + OFF_XT);
  unsigned short* phi = (unsigned short*)(ws + OFF_PHI);
  unsigned short* plo = (unsigned short*)(ws + OFF_PLO);
  unsigned short* qhi = (unsigned short*)(ws + OFF_QHI);
  unsigned short* qlo = (unsigned short*)(ws + OFF_QLO);
  unsigned int* ctr = (unsigned int*)(ws + OFF_CTR);
  float* out = (float*)d_out;

  // zero output (we accumulate into it) and h buffers + barrier counter
  hipMemsetAsync(d_out, 0, (size_t)NB * NT_ * 4, stream);
  hipMemsetAsync(ws + OFF_PHI, 0, (OFF_CTR + 64) - OFF_PHI, stream);

  prep_xT<<<1024, 256, 0, stream>>>(inp, xT);
  prep_w<<<12288, 256, 0, stream>>>(Wh0, Wx1, Wh1, wsl);

  lstm_main<<<NGRID, 512, 65536, stream>>>(xT, wsl, Wx0, b0, b1, Wf, bf,
                                           phi, plo, qhi, qlo, ctr, out);
}